// Round 13
// baseline (49.078 us; speedup 1.0000x reference)
//
#include <hip/hip_runtime.h>
#include <cstdint>
#include <cstddef>

#define NCLS 80
#define KTOP 10
#define NG   20
#define NB   32
#define A0   6400
#define A1   1600
#define A2   400
#define ATOT 8400
#define EPSF 1e-9f

#define NTHR   (NB * ATOT)
#define NBLK   ((NTHR + 255) / 256)
#define RECTCAP 512   // max rect anchors per (b,g,lvl): boxes <=136px -> <=19^2=361
#define NRES   (NB * 3)   // resolve blocks: one per (b, level)

// ---------------------------------------------------------------------------
// K1: per (b, anchor): in-box-any test; in-box anchors compute SINGLE-PASS
// logZ = log(sum(exp(x))) (N(0,1) inputs: no overflow; validated R12).
// Dense grid (R9/R11 lesson: softmax only in dense many-wave grids).
// Thread 0 zeroes the done-ticket for K3.
// ---------------------------------------------------------------------------
__global__ __launch_bounds__(256) void k1_logz(
    const float* __restrict__ cls0, const float* __restrict__ cls1,
    const float* __restrict__ cls2,
    const float* __restrict__ anchors, const float* __restrict__ gtb,
    float* __restrict__ logZ, int* __restrict__ done)
{
    int t = blockIdx.x * 256 + threadIdx.x;
    if (t == 0) *done = 0;             // ticket reset (K3 runs strictly after K1)
    if (t >= NTHR) return;
    int b = t / ATOT, a = t % ATOT;

    const float* cls; int A; float stride;
    if (a < A0)           { cls = cls0; A = A0; stride = 8.f;  }
    else if (a < A0 + A1) { cls = cls1; A = A1; stride = 16.f; }
    else                  { cls = cls2; A = A2; stride = 32.f; }
    int al = (a < A0) ? a : (a < A0 + A1 ? a - A0 : a - A0 - A1);

    float ax = anchors[2 * a]     * stride;
    float ay = anchors[2 * a + 1] * stride;

    const float4* gb4 = reinterpret_cast<const float4*>(gtb + (size_t)b * NG * 4);
    bool any = false;
    #pragma unroll
    for (int g = 0; g < NG; ++g) {
        float4 gv = gb4[g];
        any = any || ((ax - gv.x > EPSF) && (ay - gv.y > EPSF) &&
                      (gv.z - ax > EPSF) && (gv.w - ay > EPSF));
    }
    if (!any) return;   // ~75% of anchors: skip the 320B cls row entirely

    const float4* crow4 = reinterpret_cast<const float4*>(cls + ((size_t)b * A + al) * NCLS);
    float s = 0.f;
    #pragma unroll
    for (int j = 0; j < NCLS / 4; ++j) {
        float4 v = crow4[j];
        s += __expf(v.x) + __expf(v.y) + __expf(v.z) + __expf(v.w);
    }
    logZ[(size_t)b * ATOT + a] = __logf(s);
}

// ---------------------------------------------------------------------------
// K2: per (b,g,level) [1 wave]: analytic in-box rectangle, metric on the fly
// from logZ/cls/reg, exact top-10 with jax.lax.top_k tie-break
// (key = met_bits<<32 | (ATOT-a); met<=EPS -> key 0). Winners to FIXED slots
// {anchor, iou_bits}, sentinel a=-1 — all KTOP slots written every call
// (poison-safe, no atomics, no mask array).
// ---------------------------------------------------------------------------
__global__ __launch_bounds__(64) void k2_topk(
    const float* __restrict__ cls0, const float* __restrict__ reg0,
    const float* __restrict__ cls1, const float* __restrict__ reg1,
    const float* __restrict__ cls2, const float* __restrict__ reg2,
    const float* __restrict__ gtb, const int* __restrict__ gtl,
    const float* __restrict__ logZ, int2* __restrict__ winners)
{
    int id  = blockIdx.x;           // (b*NG+g)*3 + lvl
    int lvl = id % 3;
    int bg  = id / 3;
    int b = bg / NG, g = bg % NG;
    int lane = threadIdx.x;

    const float* cls; const float* reg; int off, A, W; float stride;
    if (lvl == 0)      { cls = cls0; reg = reg0; off = 0;     A = A0; W = 80; stride = 8.f;  }
    else if (lvl == 1) { cls = cls1; reg = reg1; off = A0;    A = A1; W = 40; stride = 16.f; }
    else               { cls = cls2; reg = reg2; off = A0+A1; A = A2; W = 20; stride = 32.f; }

    float4 gv = reinterpret_cast<const float4*>(gtb + (size_t)b * NG * 4)[g];
    int lbl = gtl[b * NG + g];

    // conservative rect (superset); exact strict test applied per anchor below
    float inv = 1.f / stride;
    int ix0 = max(0,     (int)floorf(gv.x * inv - 0.5f));
    int ix1 = min(W - 1, (int)ceilf (gv.z * inv - 0.5f));
    int iy0 = max(0,     (int)floorf(gv.y * inv - 0.5f));
    int iy1 = min(W - 1, (int)ceilf (gv.w * inv - 0.5f));
    int nx = ix1 - ix0 + 1, ny = iy1 - iy0 + 1;
    int n = (nx > 0 && ny > 0) ? nx * ny : 0;   // NO early return: slots must be filled
    if (n > RECTCAP) n = RECTCAP;

    float area2 = (gv.z - gv.x) * (gv.w - gv.y);

    __shared__ unsigned long long key[RECTCAP];
    __shared__ float iouA[RECTCAP];
    for (int i = lane; i < n; i += 64) {
        int iy = i / nx, ix = i - iy * nx;
        int gx = ix0 + ix, gy = iy0 + iy;
        float ax = ((float)gx + 0.5f) * stride;   // bit-identical to anchors[]*stride
        float ay = ((float)gy + 0.5f) * stride;
        unsigned long long kk = 0; float iou = 0.f;
        bool ing = (ax - gv.x > EPSF) && (ay - gv.y > EPSF) &&
                   (gv.z - ax > EPSF) && (gv.w - ay > EPSF);
        if (ing) {
            int al = gy * W + gx;
            int a  = off + al;
            float4 rr = *reinterpret_cast<const float4*>(reg + ((size_t)b * A + al) * 4);
            float px1 = ax - rr.x * stride, py1 = ay - rr.y * stride;
            float px2 = ax + rr.z * stride, py2 = ay + rr.w * stride;
            float area1 = (px2 - px1) * (py2 - py1);
            float ltx = fmaxf(px1, gv.x), lty = fmaxf(py1, gv.y);
            float rbx = fminf(px2, gv.z), rby = fminf(py2, gv.w);
            float w = fmaxf(rbx - ltx, 0.f), h = fmaxf(rby - lty, 0.f);
            float inter = w * h;
            iou = inter / (area1 + area2 - inter + EPSF);
            float lz = logZ[(size_t)b * ATOT + a];
            float c  = cls[((size_t)b * A + al) * NCLS + lbl];
            float sc = __expf(c - lz);                // softmax score at gt label
            float i2 = iou * iou;
            float met = sc * (i2 * i2 * i2);          // score^1 * iou^6
            if (met > EPSF)
                kk = ((unsigned long long)__float_as_uint(met) << 32)
                   | (uint32_t)(ATOT - a);
        }
        key[i] = kk; iouA[i] = iou;
    }
    __syncthreads();

    for (int k = 0; k < KTOP; ++k) {
        unsigned long long bk = 0; int bs = -1;
        for (int i = lane; i < n; i += 64) {
            unsigned long long kk = key[i];
            if (kk > bk) { bk = kk; bs = i; }         // keys unique (idx in low bits)
        }
        #pragma unroll
        for (int sft = 32; sft > 0; sft >>= 1) {
            unsigned long long ok = __shfl_down(bk, sft);
            int os = __shfl_down(bs, sft);
            if (ok > bk) { bk = ok; bs = os; }
        }
        bk = __shfl(bk, 0); bs = __shfl(bs, 0);       // uniform
        if (bk == 0) {                                // fewer than KTOP valid
            if (lane >= k && lane < KTOP)             // sentinel-fill remaining slots
                winners[(size_t)id * KTOP + lane] = make_int2(-1, 0);
            break;
        }
        if (lane == 0) {
            int aa = ATOT - (int)(bk & 0xffffffffu);
            winners[(size_t)id * KTOP + k] = make_int2(aa, __float_as_int(iouA[bs]));
            key[bs] = 0;                              // remove winner
        }
        __syncthreads();
    }
}

// ---------------------------------------------------------------------------
// K3: one block per (b, level) [anchors never collide across levels]: stage
// the 200 winner entries in LDS; entry survives iff no same-anchor entry has
// (iou greater) or (iou equal && g lower) == jnp.argmax(where(is_pos,iou,-1))
// (beat-test validated R11). Survivors: CE = logZ - cls[label] (gathers only,
// no heavy math -> small blocks OK). Block partial -> distinct address; the
// LAST block (96-RMW ticket, cheap unlike R4's 3150) reduces the 96 partials
// via atomic-RMW reads (cross-XCD coherent) and writes the output.
// ---------------------------------------------------------------------------
__global__ __launch_bounds__(256) void k3_resolve(
    const float* __restrict__ cls0, const float* __restrict__ cls1,
    const float* __restrict__ cls2, const int* __restrict__ gtl,
    const float* __restrict__ logZ, const int2* __restrict__ winners,
    float2* __restrict__ partials, int* __restrict__ done,
    float* __restrict__ out)
{
    int id  = blockIdx.x;           // b*3 + lvl
    int lvl = id % 3;
    int b   = id / 3;
    int tid = threadIdx.x;

    const float* cls; int off, A;
    if (lvl == 0)      { cls = cls0; off = 0;     A = A0; }
    else if (lvl == 1) { cls = cls1; off = A0;    A = A1; }
    else               { cls = cls2; off = A0+A1; A = A2; }

    __shared__ int2 sh[NG * KTOP];                   // 200 entries of this (b,lvl)
    for (int i = tid; i < NG * KTOP; i += 256) {
        int g = i / KTOP, k = i % KTOP;
        sh[i] = winners[(size_t)((b * NG + g) * 3 + lvl) * KTOP + k];
    }
    __syncthreads();

    float ce = 0.f, pc = 0.f;
    if (tid < NG * KTOP) {
        int2 e = sh[tid];
        if (e.x >= 0) {
            int g = tid / KTOP;
            float eiou = __int_as_float(e.y);
            bool beaten = false;
            for (int i = 0; i < NG * KTOP; ++i) {    // LDS broadcast reads
                int2 f = sh[i];
                if (f.x == e.x) {
                    float fiou = __int_as_float(f.y);
                    int gf = i / KTOP;
                    if (fiou > eiou || (fiou == eiou && gf < g)) beaten = true;
                }
            }
            if (!beaten) {
                int a = e.x, al = a - off;
                int tl = gtl[b * NG + g];
                ce = logZ[(size_t)b * ATOT + a]
                   - cls[((size_t)b * A + al) * NCLS + tl];  // -log_softmax[target]
                pc = 1.f;
            }
        }
    }

    #pragma unroll
    for (int sft = 32; sft > 0; sft >>= 1) {
        ce += __shfl_down(ce, sft);
        pc += __shfl_down(pc, sft);
    }
    __shared__ float sce[4];
    __shared__ float spc[4];
    __shared__ int lastFlag;
    int wid = tid >> 6, lane = tid & 63;
    if (lane == 0) { sce[wid] = ce; spc[wid] = pc; }
    __syncthreads();
    if (tid == 0) {
        float2 p;
        p.x = sce[0] + sce[1] + sce[2] + sce[3];
        p.y = spc[0] + spc[1] + spc[2] + spc[3];
        partials[id] = p;                 // distinct address per block
        __threadfence();                  // publish before ticket
        int prev = atomicAdd(done, 1);
        lastFlag = (prev == NRES - 1) ? 1 : 0;
    }
    __syncthreads();

    if (lastFlag) {                       // last block finalizes
        float* pf = (float*)partials;
        float c2 = 0.f, p2 = 0.f;
        if (tid < NRES) {                 // parallel atomic-RMW reads: coherent
            c2 = atomicAdd(&pf[2 * tid],     0.f);
            p2 = atomicAdd(&pf[2 * tid + 1], 0.f);
        }
        #pragma unroll
        for (int sft = 32; sft > 0; sft >>= 1) {
            c2 += __shfl_down(c2, sft);
            p2 += __shfl_down(p2, sft);
        }
        __syncthreads();                  // reuse sce/spc safely
        if (lane == 0) { sce[wid] = c2; spc[wid] = p2; }
        __syncthreads();
        if (tid == 0) {
            float total = sce[0] + sce[1] + sce[2] + sce[3];
            int   n     = (int)(spc[0] + spc[1] + spc[2] + spc[3]);
            float denom = (float)(n < 1 ? 1 : n);
            out[0] = total / denom;
            out[1] = (float)n;
        }
    }
}

extern "C" void kernel_launch(void* const* d_in, const int* in_sizes, int n_in,
                              void* d_out, int out_size, void* d_ws, size_t ws_size,
                              hipStream_t stream)
{
    const float* cls0 = (const float*)d_in[0];
    const float* reg0 = (const float*)d_in[1];
    const float* cls1 = (const float*)d_in[2];
    const float* reg1 = (const float*)d_in[3];
    const float* cls2 = (const float*)d_in[4];
    const float* reg2 = (const float*)d_in[5];
    const float* anchors = (const float*)d_in[6];
    const float* gtb  = (const float*)d_in[7];
    const int*   gtl  = (const int*)d_in[8];

    // workspace: logZ written before read (in-box anchors only, and only those
    // are ever read); winners fully rewritten (incl. sentinels) every call;
    // partials fully rewritten; done re-zeroed by K1 each call. Poison-safe.
    float*  logZ     = (float*)d_ws;                               // NB*ATOT
    int2*   winners  = (int2*)(logZ + (size_t)NB * ATOT);          // NB*NG*3*KTOP
    float2* partials = (float2*)(winners + (size_t)NB * NG * 3 * KTOP); // NRES
    int*    done     = (int*)(partials + NRES);

    k1_logz<<<NBLK, 256, 0, stream>>>(cls0, cls1, cls2, anchors, gtb, logZ, done);
    k2_topk<<<NB * NG * 3, 64, 0, stream>>>(cls0, reg0, cls1, reg1, cls2, reg2,
                                            gtb, gtl, logZ, winners);
    k3_resolve<<<NRES, 256, 0, stream>>>(cls0, cls1, cls2, gtl, logZ, winners,
                                         partials, done, (float*)d_out);
}

// Round 14
// 37.925 us; speedup vs baseline: 1.2941x; 1.2941x over previous
//
#include <hip/hip_runtime.h>
#include <cstdint>
#include <cstddef>

#define NCLS 80
#define KTOP 10
#define NG   20
#define NB   32
#define A0   6400
#define A1   1600
#define A2   400
#define ATOT 8400
#define EPSF 1e-9f

#define NTHR   (NB * ATOT)
#define NBLK   ((NTHR + 255) / 256)
#define NBLK4  ((NTHR / 4 + 255) / 256)   // phase3: 4 anchors/thread
#define RECTCAP 512   // max rect anchors per (b,g,lvl): boxes <=136px -> <=19^2=361

// ---------------------------------------------------------------------------
// Phase 1 (R12-validated best): per (b, anchor): zero mask word; in-box-any
// test; in-box anchors compute SINGLE-PASS logZ = log(sum(exp(x)))
// (N(0,1) inputs: no overflow; tolerance 282 >> ULP shift).
// Dense grid (R9/R11/R13 lesson: heavy per-anchor math ONLY in dense grids).
// ---------------------------------------------------------------------------
__global__ __launch_bounds__(256) void phase1_logz(
    const float* __restrict__ cls0, const float* __restrict__ cls1,
    const float* __restrict__ cls2,
    const float* __restrict__ anchors, const float* __restrict__ gtb,
    float* __restrict__ logZ, uint32_t* __restrict__ mask)
{
    int t = blockIdx.x * 256 + threadIdx.x;
    if (t >= NTHR) return;
    mask[t] = 0;                       // free coalesced zeroing (vs 40us memset)
    int b = t / ATOT, a = t % ATOT;

    const float* cls; int A; float stride;
    if (a < A0)           { cls = cls0; A = A0; stride = 8.f;  }
    else if (a < A0 + A1) { cls = cls1; A = A1; stride = 16.f; }
    else                  { cls = cls2; A = A2; stride = 32.f; }
    int al = (a < A0) ? a : (a < A0 + A1 ? a - A0 : a - A0 - A1);

    float ax = anchors[2 * a]     * stride;
    float ay = anchors[2 * a + 1] * stride;

    const float4* gb4 = reinterpret_cast<const float4*>(gtb + (size_t)b * NG * 4);
    bool any = false;
    #pragma unroll
    for (int g = 0; g < NG; ++g) {
        float4 gv = gb4[g];
        any = any || ((ax - gv.x > EPSF) && (ay - gv.y > EPSF) &&
                      (gv.z - ax > EPSF) && (gv.w - ay > EPSF));
    }
    if (!any) return;   // ~75% of anchors: skip the 320B cls row entirely

    const float4* crow4 = reinterpret_cast<const float4*>(cls + ((size_t)b * A + al) * NCLS);
    float s = 0.f;
    #pragma unroll
    for (int j = 0; j < NCLS / 4; ++j) {
        float4 v = crow4[j];
        s += __expf(v.x) + __expf(v.y) + __expf(v.z) + __expf(v.w);
    }
    logZ[(size_t)b * ATOT + a] = __logf(s);
}

// ---------------------------------------------------------------------------
// Phase 2 (R6/R12-validated, 64 thr): per (b,g,level): analytic in-box
// rectangle, metric on the fly from logZ/cls/reg, exact top-10 with
// jax.lax.top_k tie-break (key = met_bits<<32 | (ATOT-a); met<=EPS -> key 0).
// ---------------------------------------------------------------------------
__global__ __launch_bounds__(64) void phase2_topk(
    const float* __restrict__ cls0, const float* __restrict__ reg0,
    const float* __restrict__ cls1, const float* __restrict__ reg1,
    const float* __restrict__ cls2, const float* __restrict__ reg2,
    const float* __restrict__ gtb, const int* __restrict__ gtl,
    const float* __restrict__ logZ, uint32_t* __restrict__ mask)
{
    int id  = blockIdx.x;           // (b*NG+g)*3 + lvl
    int lvl = id % 3;
    int bg  = id / 3;
    int b = bg / NG, g = bg % NG;
    int lane = threadIdx.x;

    const float* cls; const float* reg; int off, A, W; float stride;
    if (lvl == 0)      { cls = cls0; reg = reg0; off = 0;     A = A0; W = 80; stride = 8.f;  }
    else if (lvl == 1) { cls = cls1; reg = reg1; off = A0;    A = A1; W = 40; stride = 16.f; }
    else               { cls = cls2; reg = reg2; off = A0+A1; A = A2; W = 20; stride = 32.f; }

    float4 gv = reinterpret_cast<const float4*>(gtb + (size_t)b * NG * 4)[g];
    int lbl = gtl[b * NG + g];

    // conservative rect (superset); exact strict test applied per anchor below
    float inv = 1.f / stride;
    int ix0 = max(0,     (int)floorf(gv.x * inv - 0.5f));
    int ix1 = min(W - 1, (int)ceilf (gv.z * inv - 0.5f));
    int iy0 = max(0,     (int)floorf(gv.y * inv - 0.5f));
    int iy1 = min(W - 1, (int)ceilf (gv.w * inv - 0.5f));
    int nx = ix1 - ix0 + 1, ny = iy1 - iy0 + 1;
    if (nx <= 0 || ny <= 0) return;
    int n = nx * ny; if (n > RECTCAP) n = RECTCAP;

    float area2 = (gv.z - gv.x) * (gv.w - gv.y);

    __shared__ unsigned long long key[RECTCAP];
    for (int i = lane; i < n; i += 64) {
        int iy = i / nx, ix = i - iy * nx;
        int gx = ix0 + ix, gy = iy0 + iy;
        float ax = ((float)gx + 0.5f) * stride;   // bit-identical to anchors[]*stride
        float ay = ((float)gy + 0.5f) * stride;
        unsigned long long kk = 0;
        bool ing = (ax - gv.x > EPSF) && (ay - gv.y > EPSF) &&
                   (gv.z - ax > EPSF) && (gv.w - ay > EPSF);
        if (ing) {
            int al = gy * W + gx;
            int a  = off + al;
            float4 rr = *reinterpret_cast<const float4*>(reg + ((size_t)b * A + al) * 4);
            float px1 = ax - rr.x * stride, py1 = ay - rr.y * stride;
            float px2 = ax + rr.z * stride, py2 = ay + rr.w * stride;
            float area1 = (px2 - px1) * (py2 - py1);
            float ltx = fmaxf(px1, gv.x), lty = fmaxf(py1, gv.y);
            float rbx = fminf(px2, gv.z), rby = fminf(py2, gv.w);
            float w = fmaxf(rbx - ltx, 0.f), h = fmaxf(rby - lty, 0.f);
            float inter = w * h;
            float iou = inter / (area1 + area2 - inter + EPSF);
            float lz = logZ[(size_t)b * ATOT + a];
            float c  = cls[((size_t)b * A + al) * NCLS + lbl];
            float sc = __expf(c - lz);                // softmax score at gt label
            float i2 = iou * iou;
            float met = sc * (i2 * i2 * i2);          // score^1 * iou^6
            if (met > EPSF)
                kk = ((unsigned long long)__float_as_uint(met) << 32)
                   | (uint32_t)(ATOT - a);
        }
        key[i] = kk;
    }
    __syncthreads();

    for (int k = 0; k < KTOP; ++k) {
        unsigned long long bk = 0; int bs = -1;
        for (int i = lane; i < n; i += 64) {
            unsigned long long kk = key[i];
            if (kk > bk) { bk = kk; bs = i; }         // keys unique (idx in low bits)
        }
        #pragma unroll
        for (int sft = 32; sft > 0; sft >>= 1) {
            unsigned long long ok = __shfl_down(bk, sft);
            int os = __shfl_down(bs, sft);
            if (ok > bk) { bk = ok; bs = os; }
        }
        bk = __shfl(bk, 0); bs = __shfl(bs, 0);       // uniform break decision
        if (bk == 0) break;                           // fewer than 10 valid: all taken
        if (lane == 0) {
            int aa = ATOT - (int)(bk & 0xffffffffu);
            atomicOr(&mask[(size_t)b * ATOT + aa], 1u << g);
            key[bs] = 0;                              // remove winner
        }
        __syncthreads();
    }
}

// ---------------------------------------------------------------------------
// Phase 3 (R12 logic, 4 anchors/thread): uint4 mask loads (mask is ~95.5%
// zeros; ATOT%4==0 so a 4-group never crosses a batch). Per positive:
// resolve multi-assignment by best IoU (iou desc, g asc), CE = logZ -
// cls[label]. Block partial -> distinct address (R4 lesson).
// ---------------------------------------------------------------------------
__global__ __launch_bounds__(256) void phase3_loss(
    const float* __restrict__ cls0, const float* __restrict__ reg0,
    const float* __restrict__ cls1, const float* __restrict__ reg1,
    const float* __restrict__ cls2, const float* __restrict__ reg2,
    const float* __restrict__ anchors, const float* __restrict__ gtb,
    const int* __restrict__ gtl,
    const uint32_t* __restrict__ mask, const float* __restrict__ logZ,
    float2* __restrict__ partials)
{
    int t4 = blockIdx.x * 256 + threadIdx.x;
    float ce = 0.f; float pc = 0.f;

    if (t4 < NTHR / 4) {
        uint4 m4 = reinterpret_cast<const uint4*>(mask)[t4];
        if (m4.x | m4.y | m4.z | m4.w) {
            uint32_t mks[4] = { m4.x, m4.y, m4.z, m4.w };
            int base = t4 * 4;
            int b = base / ATOT;                      // 4-group stays in one b
            const float4* gb4 = reinterpret_cast<const float4*>(gtb + (size_t)b * NG * 4);
            #pragma unroll
            for (int q = 0; q < 4; ++q) {
                uint32_t mk = mks[q];
                if (!mk) continue;
                int a = (base + q) % ATOT;

                const float* cls; const float* reg; int off, A; float stride;
                if (a < A0)           { cls = cls0; reg = reg0; off = 0;     A = A0; stride = 8.f;  }
                else if (a < A0 + A1) { cls = cls1; reg = reg1; off = A0;    A = A1; stride = 16.f; }
                else                  { cls = cls2; reg = reg2; off = A0+A1; A = A2; stride = 32.f; }
                int al = a - off;

                float ax = anchors[2 * a]     * stride;
                float ay = anchors[2 * a + 1] * stride;
                float4 rr = *reinterpret_cast<const float4*>(reg + ((size_t)b * A + al) * 4);
                float px1 = ax - rr.x * stride, py1 = ay - rr.y * stride;
                float px2 = ax + rr.z * stride, py2 = ay + rr.w * stride;
                float area1 = (px2 - px1) * (py2 - py1);

                float bestI = -1.f; int bestG = 0;
                uint32_t mm = mk;
                while (mm) {
                    int g = __ffs(mm) - 1; mm &= mm - 1;
                    float4 gv = gb4[g];
                    float ltx = fmaxf(px1, gv.x), lty = fmaxf(py1, gv.y);
                    float rbx = fminf(px2, gv.z), rby = fminf(py2, gv.w);
                    float w = fmaxf(rbx - ltx, 0.f), h = fmaxf(rby - lty, 0.f);
                    float inter = w * h;
                    float area2 = (gv.z - gv.x) * (gv.w - gv.y);
                    float iou = inter / (area1 + area2 - inter + EPSF);
                    if (iou > bestI) { bestI = iou; bestG = g; }  // g asc: lowest on tie
                }
                int tl = gtl[b * NG + bestG];
                ce += logZ[(size_t)b * ATOT + a]
                    - cls[((size_t)b * A + al) * NCLS + tl];      // -log_softmax[tgt]
                pc += 1.f;
            }
        }
    }

    #pragma unroll
    for (int sft = 32; sft > 0; sft >>= 1) {
        ce += __shfl_down(ce, sft);
        pc += __shfl_down(pc, sft);
    }
    __shared__ float sce[4];
    __shared__ float spc[4];
    int wid = threadIdx.x >> 6, lane = threadIdx.x & 63;
    if (lane == 0) { sce[wid] = ce; spc[wid] = pc; }
    __syncthreads();
    if (threadIdx.x == 0) {
        float2 p;
        p.x = sce[0] + sce[1] + sce[2] + sce[3];
        p.y = spc[0] + spc[1] + spc[2] + spc[3];
        partials[blockIdx.x] = p;        // distinct address per block: no contention
    }
}

// ---------------------------------------------------------------------------
// Finalize: single block reduces per-block partials, writes output.
// ---------------------------------------------------------------------------
__global__ __launch_bounds__(256) void finalize_loss(
    const float2* __restrict__ partials, float* __restrict__ out)
{
    float ce = 0.f, pc = 0.f;
    for (int i = threadIdx.x; i < NBLK4; i += 256) {
        float2 p = partials[i];
        ce += p.x; pc += p.y;
    }
    #pragma unroll
    for (int sft = 32; sft > 0; sft >>= 1) {
        ce += __shfl_down(ce, sft);
        pc += __shfl_down(pc, sft);
    }
    __shared__ float sce[4];
    __shared__ float spc[4];
    int wid = threadIdx.x >> 6, lane = threadIdx.x & 63;
    if (lane == 0) { sce[wid] = ce; spc[wid] = pc; }
    __syncthreads();
    if (threadIdx.x == 0) {
        float total = sce[0] + sce[1] + sce[2] + sce[3];
        int   n     = (int)(spc[0] + spc[1] + spc[2] + spc[3]);
        float denom = (float)(n < 1 ? 1 : n);
        out[0] = total / denom;
        out[1] = (float)n;
    }
}

extern "C" void kernel_launch(void* const* d_in, const int* in_sizes, int n_in,
                              void* d_out, int out_size, void* d_ws, size_t ws_size,
                              hipStream_t stream)
{
    const float* cls0 = (const float*)d_in[0];
    const float* reg0 = (const float*)d_in[1];
    const float* cls1 = (const float*)d_in[2];
    const float* reg1 = (const float*)d_in[3];
    const float* cls2 = (const float*)d_in[4];
    const float* reg2 = (const float*)d_in[5];
    const float* anchors = (const float*)d_in[6];
    const float* gtb  = (const float*)d_in[7];
    const int*   gtl  = (const int*)d_in[8];

    // workspace layout (everything read is rewritten earlier in the same call)
    float*    logZ     = (float*)d_ws;                              // NB*ATOT
    uint32_t* mask     = (uint32_t*)(logZ + (size_t)NB * ATOT);     // NB*ATOT (16B-aligned)
    float2*   partials = (float2*)(mask + (size_t)NB * ATOT);       // NBLK4 float2

    phase1_logz<<<NBLK, 256, 0, stream>>>(cls0, cls1, cls2, anchors, gtb, logZ, mask);
    phase2_topk<<<NB * NG * 3, 64, 0, stream>>>(cls0, reg0, cls1, reg1, cls2, reg2,
                                                gtb, gtl, logZ, mask);
    phase3_loss<<<NBLK4, 256, 0, stream>>>(cls0, reg0, cls1, reg1, cls2, reg2,
                                           anchors, gtb, gtl, mask, logZ, partials);
    finalize_loss<<<1, 256, 0, stream>>>(partials, (float*)d_out);
}